// Round 8
// baseline (851.536 us; speedup 1.0000x reference)
//
#include <hip/hip_runtime.h>
#include <cmath>
#include <cstdint>

#define NPOS 49
#define NANCH 588

// ---------------------------------------------------------------------------
// Weight transposes.
// w1:  [256][512] -> float4-interleaved w1t[q*256+o][4] = w1[o][4q..4q+3]
// w2/3/4: [o][c][3][3] -> k-contiguous wNt[(c*256+o)*12 + k]  (k<9, pad 12)
// heads:  wbt[ck*48+o], wct[ck*12+o]
// ---------------------------------------------------------------------------
__global__ void transpose_all(
    const float* __restrict__ w1, const float* __restrict__ w2,
    const float* __restrict__ w3, const float* __restrict__ w4,
    const float* __restrict__ wb, const float* __restrict__ wc,
    float* __restrict__ w1t, float* __restrict__ w2t, float* __restrict__ w3t,
    float* __restrict__ w4t, float* __restrict__ wbt, float* __restrict__ wct) {
  int idx = blockIdx.x * blockDim.x + threadIdx.x;
  if (idx < 131072) {
    int o = idx / 512, c = idx % 512;
    w1t[((c >> 2) * 256 + o) * 4 + (c & 3)] = w1[idx];
    return;
  }
  idx -= 131072;
  if (idx < 589824) {
    int o = idx / 2304, ck = idx % 2304, c = ck / 9, k = ck - c * 9;
    w2t[(c * 256 + o) * 12 + k] = w2[idx]; return;
  }
  idx -= 589824;
  if (idx < 589824) {
    int o = idx / 2304, ck = idx % 2304, c = ck / 9, k = ck - c * 9;
    w3t[(c * 256 + o) * 12 + k] = w3[idx]; return;
  }
  idx -= 589824;
  if (idx < 589824) {
    int o = idx / 2304, ck = idx % 2304, c = ck / 9, k = ck - c * 9;
    w4t[(c * 256 + o) * 12 + k] = w4[idx]; return;
  }
  idx -= 589824;
  if (idx < 110592) { int o = idx / 2304, ck = idx % 2304; wbt[ck * 48 + o] = wb[idx]; return; }
  idx -= 110592;
  if (idx < 27648)  { int o = idx / 2304, ck = idx % 2304; wct[ck * 12 + o] = wc[idx]; return; }
}

// ---------------------------------------------------------------------------
// conv 1x1 (512 -> 256) + bias + BN + ReLU.
// Grid = 2*B: block = (image, o-half of 128).  512 thr = 128 slots x 4 cg.
// Two-phase staging of 256 ch -> LDS [256][52] = 53,248 B -> 2 blocks/CU.
// ---------------------------------------------------------------------------
__global__ __launch_bounds__(512) __attribute__((amdgpu_waves_per_eu(4, 4)))
void conv1x1_bn(
    const float* __restrict__ in, const float* __restrict__ wt_f,
    const float* __restrict__ bias, const float* __restrict__ gg,
    const float* __restrict__ be, const float* __restrict__ mu,
    const float* __restrict__ var, float* __restrict__ out) {
  __shared__ float smem[256 * 52];  // 53,248 B
  const int blk = blockIdx.x, t = threadIdx.x;
  const int b = blk >> 1, oh = blk & 1;
  const int slot = t & 127, cg = t >> 7;   // cg in 0..3
  const int og = oh * 128 + slot;
  const float* inb = in + (size_t)b * (512 * NPOS);
  const float4* wq = (const float4*)wt_f;  // [128 quads][256 o]
  float acc[NPOS];
#pragma unroll
  for (int p = 0; p < NPOS; ++p) acc[p] = 0.f;
  for (int h = 0; h < 2; ++h) {
    __syncthreads();                       // WAR vs previous phase compute
    for (int i = t; i < 256 * NPOS; i += 512) {
      int c = i / NPOS, p = i - c * NPOS;
      smem[c * 52 + p] = inb[(h * 256 + c) * NPOS + p];
    }
    __syncthreads();
    const int q0 = h * 64 + cg * 16;       // 16 quads (64 ch) per cg per phase
    float4 wcur = wq[q0 * 256 + og];
    for (int q = q0; q < q0 + 16; ++q) {
      int nq = (q + 1 < q0 + 16) ? q + 1 : q;
      float4 wnxt = wq[nq * 256 + og];     // prefetch next quad
      const int clb = (q - h * 64) * 4;    // local channel base in tile
#pragma unroll
      for (int j = 0; j < 4; ++j) {
        float wv = (j == 0) ? wcur.x : (j == 1) ? wcur.y : (j == 2) ? wcur.z : wcur.w;
        const float* row = smem + (clb + j) * 52;
        const float4* tr = (const float4*)row;
#pragma unroll
        for (int jj = 0; jj < 12; ++jj) {
          float4 qv = tr[jj];
          acc[4 * jj + 0] = fmaf(wv, qv.x, acc[4 * jj + 0]);
          acc[4 * jj + 1] = fmaf(wv, qv.y, acc[4 * jj + 1]);
          acc[4 * jj + 2] = fmaf(wv, qv.z, acc[4 * jj + 2]);
          acc[4 * jj + 3] = fmaf(wv, qv.w, acc[4 * jj + 3]);
        }
        acc[48] = fmaf(wv, row[48], acc[48]);
      }
      wcur = wnxt;
    }
  }
  __syncthreads();
  float* P0 = smem;            // [128 slots][49]
  float* P1 = smem + 6272;
  if (cg == 1) { for (int p = 0; p < NPOS; ++p) P0[slot * NPOS + p] = acc[p]; }
  if (cg == 3) { for (int p = 0; p < NPOS; ++p) P1[slot * NPOS + p] = acc[p]; }
  __syncthreads();
  if (cg == 0) { for (int p = 0; p < NPOS; ++p) acc[p] += P0[slot * NPOS + p]; }
  if (cg == 2) { for (int p = 0; p < NPOS; ++p) acc[p] += P1[slot * NPOS + p]; }
  __syncthreads();
  if (cg == 2) { for (int p = 0; p < NPOS; ++p) P0[slot * NPOS + p] = acc[p]; }
  __syncthreads();
  if (cg == 0) {
    float scale = gg[og] / sqrtf(var[og] + 1e-5f);
    float add = (bias[og] - mu[og]) * scale + be[og];
#pragma unroll
    for (int p = 0; p < NPOS; ++p) {
      float v = (acc[p] + P0[slot * NPOS + p]) * scale + add;
      P1[slot * NPOS + p] = v > 0.f ? v : 0.f;   // final [128 o][49]
    }
  }
  __syncthreads();
  float* outb = out + (size_t)b * (256 * NPOS) + oh * (128 * NPOS);
  for (int i = t; i < 128 * NPOS; i += 512) outb[i] = P1[i];
}

// ---------------------------------------------------------------------------
// conv 3x3 pad1 (256 -> 256) + bias + BN + ReLU.
// Grid = 2*B, compact tile [256][7][8] = 57,344 B -> 2 blocks/CU.
// waves_per_eu(4,4): pin allocator at 4 waves/EU so it allocates up to 128
// VGPRs instead of squeezing to 64 + AGPR copies (R7: VGPR=64, +25% VALU).
// ---------------------------------------------------------------------------
#define LOADROW2(dst, base, yy)                                         \
  do {                                                                  \
    const float4* q4_ = (const float4*)((base) + (yy) * 8);             \
    float4 a_ = q4_[0], b_ = q4_[1];                                    \
    dst[0] = 0.f;                                                       \
    dst[1] = a_.x; dst[2] = a_.y; dst[3] = a_.z; dst[4] = a_.w;         \
    dst[5] = b_.x; dst[6] = b_.y; dst[7] = b_.z; dst[8] = b_.w;         \
  } while (0)

#define FMA9(accbase, rt, rc, rb)                                       \
  do {                                                                  \
    _Pragma("unroll")                                                   \
    for (int x = 0; x < 7; ++x) {                                       \
      float s = acc[(accbase) + x];                                     \
      s = fmaf(wa0.x, rt[x],     s);                                    \
      s = fmaf(wa0.y, rt[x + 1], s);                                    \
      s = fmaf(wa0.z, rt[x + 2], s);                                    \
      s = fmaf(wa0.w, rc[x],     s);                                    \
      s = fmaf(wa1.x, rc[x + 1], s);                                    \
      s = fmaf(wa1.y, rc[x + 2], s);                                    \
      s = fmaf(wa1.z, rb[x],     s);                                    \
      s = fmaf(wa1.w, rb[x + 1], s);                                    \
      s = fmaf(wa2.x, rb[x + 2], s);                                    \
      acc[(accbase) + x] = s;                                           \
    }                                                                   \
  } while (0)

__global__ __launch_bounds__(512) __attribute__((amdgpu_waves_per_eu(4, 4)))
void conv3x3_bn(
    const float* __restrict__ in, const float* __restrict__ wt,
    const float* __restrict__ bias, const float* __restrict__ gg,
    const float* __restrict__ be, const float* __restrict__ mu,
    const float* __restrict__ var, float* __restrict__ out) {
  __shared__ float smem[256 * 56];  // compact [c][7][8], 57,344 B
  const int blk = blockIdx.x, t = threadIdx.x;
  const int b = blk >> 1, oh = blk & 1;
  const int slot = t & 127, cg = t >> 7;   // cg in 0..3, 64-ch chains
  const int og = oh * 128 + slot;
  const float* inb = in + (size_t)b * (256 * NPOS);
  float4* z4 = (float4*)smem;
  for (int i = t; i < 3584; i += 512) z4[i] = make_float4(0.f, 0.f, 0.f, 0.f);
  const int c0 = cg * 64;
  const float4* wv4 = (const float4*)wt;   // [(c*256+o)*3] float4s
  float4 wa0 = wv4[(c0 * 256 + og) * 3 + 0];  // first-channel weights: issue
  float4 wa1 = wv4[(c0 * 256 + og) * 3 + 1];  // before staging to overlap
  float4 wa2 = wv4[(c0 * 256 + og) * 3 + 2];
  __syncthreads();  // zero done
  for (int i = t; i < 256 * NPOS; i += 512) {
    int c = i / NPOS, p = i - c * NPOS, y = p / 7, x = p - y * 7;
    smem[c * 56 + y * 8 + x] = inb[i];     // x=7 column stays 0
  }
  float acc[NPOS];
#pragma unroll
  for (int p = 0; p < NPOS; ++p) acc[p] = 0.f;
  __syncthreads();
  for (int cl = 0; cl < 64; ++cl) {
    const int c = c0 + cl;
    const int cn = (cl + 1 < 64) ? c + 1 : c;
    float4 na0 = wv4[(cn * 256 + og) * 3 + 0];  // prefetch next channel
    float4 na1 = wv4[(cn * 256 + og) * 3 + 1];
    float4 na2 = wv4[(cn * 256 + og) * 3 + 2];
    const float* tb = smem + c * 56;
    float R0[9], R1[9], R2[9];
    LOADROW2(R0, tb, 0);
    LOADROW2(R1, tb, 1);
    // y=0: rows 0 (w3..5), 1 (w6..8) — top row is exactly zero, skipped
#pragma unroll
    for (int x = 0; x < 7; ++x) {
      float s = acc[x];
      s = fmaf(wa0.w, R0[x],     s);
      s = fmaf(wa1.x, R0[x + 1], s);
      s = fmaf(wa1.y, R0[x + 2], s);
      s = fmaf(wa1.z, R1[x],     s);
      s = fmaf(wa1.w, R1[x + 1], s);
      s = fmaf(wa2.x, R1[x + 2], s);
      acc[x] = s;
    }
    LOADROW2(R2, tb, 2);
    FMA9(7, R0, R1, R2);       // y=1: rows 0,1,2
    LOADROW2(R0, tb, 3);
    FMA9(14, R1, R2, R0);      // y=2: rows 1,2,3
    LOADROW2(R1, tb, 4);
    FMA9(21, R2, R0, R1);      // y=3: rows 2,3,4
    LOADROW2(R2, tb, 5);
    FMA9(28, R0, R1, R2);      // y=4: rows 3,4,5
    LOADROW2(R0, tb, 6);
    FMA9(35, R1, R2, R0);      // y=5: rows 4,5,6
    // y=6: rows 5 (w0..2), 6 (w3..5) — bottom row is exactly zero, skipped
#pragma unroll
    for (int x = 0; x < 7; ++x) {
      float s = acc[42 + x];
      s = fmaf(wa0.x, R2[x],     s);
      s = fmaf(wa0.y, R2[x + 1], s);
      s = fmaf(wa0.z, R2[x + 2], s);
      s = fmaf(wa0.w, R0[x],     s);
      s = fmaf(wa1.x, R0[x + 1], s);
      s = fmaf(wa1.y, R0[x + 2], s);
      acc[42 + x] = s;
    }
    wa0 = na0; wa1 = na1; wa2 = na2;
  }
  __syncthreads();
  float* P0 = smem;            // [128 slots][49]
  float* P1 = smem + 6272;
  if (cg == 1) { for (int p = 0; p < NPOS; ++p) P0[slot * NPOS + p] = acc[p]; }
  if (cg == 3) { for (int p = 0; p < NPOS; ++p) P1[slot * NPOS + p] = acc[p]; }
  __syncthreads();
  if (cg == 0) { for (int p = 0; p < NPOS; ++p) acc[p] += P0[slot * NPOS + p]; }
  if (cg == 2) { for (int p = 0; p < NPOS; ++p) acc[p] += P1[slot * NPOS + p]; }
  __syncthreads();
  if (cg == 2) { for (int p = 0; p < NPOS; ++p) P0[slot * NPOS + p] = acc[p]; }
  __syncthreads();
  if (cg == 0) {
    float scale = gg[og] / sqrtf(var[og] + 1e-5f);
    float add = (bias[og] - mu[og]) * scale + be[og];
#pragma unroll
    for (int p = 0; p < NPOS; ++p) {
      float v = (acc[p] + P0[slot * NPOS + p]) * scale + add;
      P1[slot * NPOS + p] = v > 0.f ? v : 0.f;   // final [128 o][49]
    }
  }
  __syncthreads();
  float* outb = out + (size_t)b * (256 * NPOS) + oh * (128 * NPOS);
  for (int i = t; i < 128 * NPOS; i += 512) outb[i] = P1[i];
}

// ---------------------------------------------------------------------------
// Heads (box 48ch + cls 12ch, 3x3 pad1) + decode + sigmoid.
// Grid = 2*B: block = (image, row-group).  pg0: out rows y=0..3 (28 pos),
// pg1: y=4..6 (21 pos).  Compact tile [256][7][8] = 57,344 B -> 2 blocks/CU.
// Decode is position-local -> each block decodes its own anchors.
// ---------------------------------------------------------------------------
#define HFMA9(accbase, rt, rc, rb)                                      \
  do {                                                                  \
    _Pragma("unroll")                                                   \
    for (int x = 0; x < 7; ++x) {                                       \
      float s = acc[(accbase) + x];                                     \
      s = fmaf(wc_[0], rt[x],     s);                                   \
      s = fmaf(wc_[1], rt[x + 1], s);                                   \
      s = fmaf(wc_[2], rt[x + 2], s);                                   \
      s = fmaf(wc_[3], rc[x],     s);                                   \
      s = fmaf(wc_[4], rc[x + 1], s);                                   \
      s = fmaf(wc_[5], rc[x + 2], s);                                   \
      s = fmaf(wc_[6], rb[x],     s);                                   \
      s = fmaf(wc_[7], rb[x + 1], s);                                   \
      s = fmaf(wc_[8], rb[x + 2], s);                                   \
      acc[(accbase) + x] = s;                                           \
    }                                                                   \
  } while (0)

__global__ __launch_bounds__(512) __attribute__((amdgpu_waves_per_eu(4, 4)))
void heads_decode(
    const float* __restrict__ in, const float* __restrict__ wbt,
    const float* __restrict__ wct, const float* __restrict__ bb,
    const float* __restrict__ bc, float* __restrict__ BXg,
    float* __restrict__ SCg) {
  __shared__ float smem[14720];  // tile [256][56]=14336; P[4][60][28]+H[60][28] overlap after
  const int blk = blockIdx.x, t = threadIdx.x;
  const int b = blk >> 1, pg = blk & 1;
  float4* z4 = (float4*)smem;
  for (int i = t; i < 3584; i += 512) z4[i] = make_float4(0.f, 0.f, 0.f, 0.f);
  __syncthreads();
  const float* inb = in + (size_t)b * (256 * NPOS);
  for (int i = t; i < 256 * NPOS; i += 512) {
    int c = i / NPOS, p = i - c * NPOS, y = p / 7, x = p - y * 7;
    smem[c * 56 + y * 8 + x] = inb[i];
  }
  __syncthreads();
  float acc[28];
#pragma unroll
  for (int p = 0; p < 28; ++p) acc[p] = 0.f;
  int o = 0, cg = 0;
  if (t < 480) {
    o = t % 60; cg = t / 60;  // 8-way K-split, 32 c each
    const float* wbase; int wstr;
    if (o < 48) { wbase = wbt + o; wstr = 48; }
    else        { wbase = wct + (o - 48); wstr = 12; }
    const int c0 = cg * 32;
    float wc_[9];
#pragma unroll
    for (int k = 0; k < 9; ++k) wc_[k] = wbase[(c0 * 9 + k) * wstr];
    for (int c = c0; c < c0 + 32; ++c) {
      int cn = (c + 1 < c0 + 32) ? c + 1 : c;
      float wn_[9];
#pragma unroll
      for (int k = 0; k < 9; ++k) wn_[k] = wbase[(cn * 9 + k) * wstr];  // prefetch
      const float* tb = smem + c * 56;
      float R0[9], R1[9], R2[9];
      if (pg == 0) {
        LOADROW2(R0, tb, 0);
        LOADROW2(R1, tb, 1);
        // y=0: top zero row skipped (w3..w8 on rows 0,1) — bit-identical
#pragma unroll
        for (int x = 0; x < 7; ++x) {
          float s = acc[x];
          s = fmaf(wc_[3], R0[x],     s);
          s = fmaf(wc_[4], R0[x + 1], s);
          s = fmaf(wc_[5], R0[x + 2], s);
          s = fmaf(wc_[6], R1[x],     s);
          s = fmaf(wc_[7], R1[x + 1], s);
          s = fmaf(wc_[8], R1[x + 2], s);
          acc[x] = s;
        }
        LOADROW2(R2, tb, 2);
        HFMA9(7, R0, R1, R2);     // y=1: rows 0,1,2
        LOADROW2(R0, tb, 3);
        HFMA9(14, R1, R2, R0);    // y=2: rows 1,2,3
        LOADROW2(R1, tb, 4);
        HFMA9(21, R2, R0, R1);    // y=3: rows 2,3,4
      } else {
        LOADROW2(R0, tb, 3);
        LOADROW2(R1, tb, 4);
        LOADROW2(R2, tb, 5);
        HFMA9(0, R0, R1, R2);     // y=4: rows 3,4,5
        LOADROW2(R0, tb, 6);
        HFMA9(7, R1, R2, R0);     // y=5: rows 4,5,6
        // y=6: bottom zero row skipped (w0..w5 on rows 5,6)
#pragma unroll
        for (int x = 0; x < 7; ++x) {
          float s = acc[14 + x];
          s = fmaf(wc_[0], R2[x],     s);
          s = fmaf(wc_[1], R2[x + 1], s);
          s = fmaf(wc_[2], R2[x + 2], s);
          s = fmaf(wc_[3], R0[x],     s);
          s = fmaf(wc_[4], R0[x + 1], s);
          s = fmaf(wc_[5], R0[x + 2], s);
          acc[14 + x] = s;
        }
      }
#pragma unroll
      for (int k = 0; k < 9; ++k) wc_[k] = wn_[k];
    }
  }
  __syncthreads();
  // 8-way reduction tree over the 28-slot accumulators
  float* P = smem;               // [4][60][28] = 6720
  float* H = smem + 6720;        // [60][28]
  if (t < 480 && cg >= 4) {
#pragma unroll
    for (int p = 0; p < 28; ++p) P[((cg - 4) * 60 + o) * 28 + p] = acc[p];
  }
  __syncthreads();
  if (t < 480 && cg < 4) {
#pragma unroll
    for (int p = 0; p < 28; ++p) acc[p] += P[(cg * 60 + o) * 28 + p];
  }
  __syncthreads();
  if (t < 480 && (cg == 2 || cg == 3)) {
#pragma unroll
    for (int p = 0; p < 28; ++p) P[((cg - 2) * 60 + o) * 28 + p] = acc[p];
  }
  __syncthreads();
  if (t < 480 && cg < 2) {
#pragma unroll
    for (int p = 0; p < 28; ++p) acc[p] += P[(cg * 60 + o) * 28 + p];
  }
  __syncthreads();
  if (t < 480 && cg == 1) {
#pragma unroll
    for (int p = 0; p < 28; ++p) P[o * 28 + p] = acc[p];
  }
  __syncthreads();
  if (t < 60) {  // cg == 0
    float bsum = (o < 48) ? bb[o] : bc[o - 48];
#pragma unroll
    for (int p = 0; p < 28; ++p) H[o * 28 + p] = acc[p] + P[o * 28 + p] + bsum;
  }
  __syncthreads();
  // decode + sigmoid for this block's positions
  const int y0 = pg ? 4 : 0;
  const int npos = pg ? 21 : 28;
  const float scl[4] = {0.3f, 0.5f, 0.7f, 0.9f};
  const float rat[3] = {0.7f, 1.0f, 1.3f};
  if (t < npos * 12) {
    int pl = t / 12, a = t - pl * 12;
    int p = y0 * 7 + pl;
    int ph = p / 7, pw = p - ph * 7;
    float cx = (ph + 0.5f) / 7.0f;
    float cy = (pw + 0.5f) / 7.0f;
    int s = a / 3, r = a - s * 3;
    float rt = sqrtf(rat[r]);
    float wsz = scl[s] * rt, hsz = scl[s] / rt;
    float x1 = cx + (-wsz) * 0.5f, y1 = cy + (-hsz) * 0.5f;
    float x2 = cx + wsz * 0.5f,    y2 = cy + hsz * 0.5f;
    float acx = (x1 + x2) * 0.5f,  acy = (y1 + y2) * 0.5f;
    float asx = x2 - x1,           asy = y2 - y1;
    float bp0 = H[(a * 4 + 0) * 28 + pl];
    float bp1 = H[(a * 4 + 1) * 28 + pl];
    float bp2 = H[(a * 4 + 2) * 28 + pl];
    float bp3 = H[(a * 4 + 3) * 28 + pl];
    float pcx = bp0 * asx + acx;
    float pcy = bp1 * asy + acy;
    float psx = expf(bp2) * asx;
    float psy = expf(bp3) * asy;
    int n = p * 12 + a;
    float* bx = BXg + (size_t)b * (NANCH * 4) + n * 4;
    bx[0] = pcx - psx * 0.5f;
    bx[1] = pcy - psy * 0.5f;
    bx[2] = pcx + psx * 0.5f;
    bx[3] = pcy + psy * 0.5f;
    float lg = H[(48 + a) * 28 + pl];
    SCg[(size_t)b * NANCH + n] = 1.0f / (1.0f + expf(-lg));
  }
}

// ---------------------------------------------------------------------------
// NMS: rank sort + IoU bitmask + wave-parallel greedy scan.  512 thr, 66 KB.
// ---------------------------------------------------------------------------
__device__ inline unsigned long long shfl64(unsigned long long v, int lane) {
  int lo = __shfl((int)(unsigned)(v & 0xffffffffULL), lane, 64);
  int hi = __shfl((int)(unsigned)(v >> 32), lane, 64);
  return ((unsigned long long)(unsigned)hi << 32) | (unsigned)lo;
}

__global__ __launch_bounds__(512, 4) void nms_kernel(
    const float* __restrict__ BXg, const float* __restrict__ SCg,
    float* __restrict__ out) {
  __shared__ float smem[16576];
  unsigned long long* KEY = (unsigned long long*)smem;          // [588]
  float* SB  = smem + 1176;                                     // [588*4]
  float* SSc = smem + 3528;                                     // [588]
  float* AR  = smem + 4116;                                     // [588]
  unsigned long long* ADJ = (unsigned long long*)(smem + 4704); // [588*10]
  int* KEEP = (int*)(smem + 16464);                             // [100]
  int* CNT  = (int*)(smem + 16564);
  const int b = blockIdx.x, t = threadIdx.x;
  const float* scb = SCg + (size_t)b * NANCH;
  const float4* bxb = (const float4*)(BXg + (size_t)b * (NANCH * 4));
  for (int i = t; i < NANCH; i += 512) {
    unsigned u = __float_as_uint(scb[i]);
    u = (u & 0x80000000u) ? ~u : (u | 0x80000000u);
    u = ~u;
    KEY[i] = ((unsigned long long)u << 32) | (unsigned)i;
  }
  __syncthreads();
  for (int i = t; i < NANCH; i += 512) {
    unsigned long long k = KEY[i];
    int rank = 0;
    for (int j = 0; j < NANCH; ++j) rank += (KEY[j] < k) ? 1 : 0;
    float4 bx = bxb[i];
    ((float4*)SB)[rank] = bx;
    SSc[rank] = scb[i];
    AR[rank] = (bx.z - bx.x) * (bx.w - bx.y);
  }
  __syncthreads();
  const float4* SB4 = (const float4*)SB;
  for (int task = t; task < NANCH * 10; task += 512) {
    int i = task % NANCH, w = task / NANCH;
    float4 a = SB4[i];
    float aar = AR[i];
    int jbase = w * 64;
    int jend = NANCH - jbase; if (jend > 64) jend = 64;
    unsigned long long bits = 0;
    for (int bi = 0; bi < jend; ++bi) {
      int j = jbase + bi;
      float4 bb = SB4[j];
      float ltx = fmaxf(a.x, bb.x), lty = fmaxf(a.y, bb.y);
      float rbx = fminf(a.z, bb.z), rby = fminf(a.w, bb.w);
      float wx = rbx - ltx; wx = wx > 0.f ? wx : 0.f;
      float wy = rby - lty; wy = wy > 0.f ? wy : 0.f;
      float inter = wx * wy;
      float iou = inter / (aar + AR[j] - inter + 1e-9f);
      if (iou > 0.5f) bits |= (1ULL << bi);
    }
    ADJ[i * 10 + w] = bits;
  }
  __syncthreads();
  if (t < 64) {
    unsigned long long valid = 0, supp = 0;
    if (t < 10) {
      int jbase = t * 64;
      int jend = NANCH - jbase; if (jend > 64) jend = 64;
      for (int k = 0; k < jend; ++k)
        valid |= (unsigned long long)(SSc[jbase + k] > 0.3f ? 1 : 0) << k;
    }
    int cnt = 0;
    for (int w = 0; w < 10 && cnt < 100; ++w) {
      unsigned long long cur = shfl64(valid, w) & ~shfl64(supp, w);
      while (cur && cnt < 100) {
        int bpos = (int)__builtin_ctzll(cur);
        int i = w * 64 + bpos;
        if (t == 0) KEEP[cnt] = i;
        cnt++;
        unsigned long long a = (t < 10) ? ADJ[i * 10 + t] : 0ULL;
        if (t < w) a = 0ULL;
        else if (t == w) a &= ~((2ULL << bpos) - 1ULL);
        supp |= a;
        unsigned long long aw = shfl64(a, w);
        cur &= ~aw;
        cur &= ~(1ULL << bpos);
      }
    }
    if (t == 0) *CNT = cnt;
  }
  __syncthreads();
  int cnt = *CNT;
  if (t < 100) {
    float4 bx = make_float4(0.f, 0.f, 0.f, 0.f);
    float s = 0.f, vld = 0.f;
    if (t < cnt) {
      int i = KEEP[t];
      bx = SB4[i];
      s = SSc[i];
      vld = 1.f;
    }
    float* ob = out + (size_t)b * 600 + t * 6;
    ob[0] = bx.x; ob[1] = bx.y; ob[2] = bx.z; ob[3] = bx.w;
    ob[4] = s;    ob[5] = vld;
  }
}

// ---------------------------------------------------------------------------
extern "C" void kernel_launch(void* const* d_in, const int* in_sizes, int n_in,
                              void* d_out, int out_size, void* d_ws, size_t ws_size,
                              hipStream_t stream) {
  const float* feat = (const float*)d_in[0];
  const float* w1  = (const float*)d_in[1];
  const float* b1  = (const float*)d_in[2];
  const float* g1  = (const float*)d_in[3];
  const float* be1 = (const float*)d_in[4];
  const float* mu1 = (const float*)d_in[5];
  const float* v1  = (const float*)d_in[6];
  const float* w2  = (const float*)d_in[7];
  const float* b2  = (const float*)d_in[8];
  const float* g2  = (const float*)d_in[9];
  const float* be2 = (const float*)d_in[10];
  const float* mu2 = (const float*)d_in[11];
  const float* v2  = (const float*)d_in[12];
  const float* w3  = (const float*)d_in[13];
  const float* b3  = (const float*)d_in[14];
  const float* g3  = (const float*)d_in[15];
  const float* be3 = (const float*)d_in[16];
  const float* mu3 = (const float*)d_in[17];
  const float* v3  = (const float*)d_in[18];
  const float* w4  = (const float*)d_in[19];
  const float* b4  = (const float*)d_in[20];
  const float* g4  = (const float*)d_in[21];
  const float* be4 = (const float*)d_in[22];
  const float* mu4 = (const float*)d_in[23];
  const float* v4  = (const float*)d_in[24];
  const float* wcls = (const float*)d_in[25];
  const float* bcls = (const float*)d_in[26];
  const float* wbox = (const float*)d_in[27];
  const float* bbox = (const float*)d_in[28];

  const int B = in_sizes[0] / (512 * NPOS);
  float* ws  = (float*)d_ws;
  size_t xsz = (size_t)B * 256 * NPOS;
  float* xa  = ws;
  float* xb  = xa + xsz;
  float* w1t = xb + xsz;
  float* w2t = w1t + 131072;
  float* w3t = w2t + 786432;   // 256*256*12 (k-padded)
  float* w4t = w3t + 786432;
  float* wbt = w4t + 786432;
  float* wct = wbt + 110592;
  float* BXg = wct + 27648;
  float* SCg = BXg + (size_t)B * (NANCH * 4);

  transpose_all<<<(2038784 + 255) / 256, 256, 0, stream>>>(
      w1, w2, w3, w4, wbox, wcls, w1t, w2t, w3t, w4t, wbt, wct);
  conv1x1_bn<<<2 * B, 512, 0, stream>>>(feat, w1t, b1, g1, be1, mu1, v1, xa);
  conv3x3_bn<<<2 * B, 512, 0, stream>>>(xa, w2t, b2, g2, be2, mu2, v2, xb);
  conv3x3_bn<<<2 * B, 512, 0, stream>>>(xb, w3t, b3, g3, be3, mu3, v3, xa);
  conv3x3_bn<<<2 * B, 512, 0, stream>>>(xa, w4t, b4, g4, be4, mu4, v4, xb);
  heads_decode<<<2 * B, 512, 0, stream>>>(xb, wbt, wct, bbox, bcls, BXg, SCg);
  nms_kernel<<<B, 512, 0, stream>>>(BXg, SCg, (float*)d_out);
}